// Round 13
// baseline (572.435 us; speedup 1.0000x reference)
//
#include <hip/hip_runtime.h>
#include <hip/hip_bf16.h>

typedef __attribute__((ext_vector_type(8))) short bf16x8;
typedef __attribute__((ext_vector_type(4))) float f32x4;

#define NROWS 262144
#define MBLK  32
#define NBLKS (NROWS / MBLK)   /* 8192 */

// ---------------------------------------------------------------------------
// Weight prep (layout identical to R9): B-fragment keyed by (w,g,kk):
//   elem (w,g,kk,lane,j) = Wbig[g][n = w*16 + (lane&15)]
//                                [k = kk*32 + (lane>>4)*8 + j]
//   at offset ((w*32 + g*8 + kk)*64 + lane)*8 + j.  RNE hi/lo split.
// ---------------------------------------------------------------------------
__global__ void prep_weights(
    const float* __restrict__ Wi, const float* __restrict__ Ui,
    const float* __restrict__ Wf, const float* __restrict__ Uf,
    const float* __restrict__ Wo, const float* __restrict__ Uo,
    const float* __restrict__ Wz, const float* __restrict__ Uz,
    ushort* __restrict__ hi, ushort* __restrict__ lo)
{
    int idx = blockIdx.x * 256 + threadIdx.x;   // 0..131071
    int j    = idx & 7;
    int lane = (idx >> 3) & 63;
    int kk   = (idx >> 9) & 7;
    int g    = (idx >> 12) & 3;
    int w    = (idx >> 14) & 7;
    int n = w * 16 + (lane & 15);
    int k = kk * 32 + (lane >> 4) * 8 + j;
    const float* W; const float* U;
    if (g == 0)      { W = Wi; U = Ui; }
    else if (g == 1) { W = Wf; U = Uf; }
    else if (g == 2) { W = Wo; U = Uo; }
    else             { W = Wz; U = Uz; }
    float v = (k < 128) ? W[n * 128 + k] : U[n * 128 + (k - 128)];
    __hip_bfloat16 hb = __float2bfloat16(v);
    float r = v - __bfloat162float(hb);
    __hip_bfloat16 lb = __float2bfloat16(r);
    hi[idx] = *reinterpret_cast<ushort*>(&hb);
    lo[idx] = *reinterpret_cast<ushort*>(&lb);
}

// ---------------------------------------------------------------------------
// Main fused kernel. 8192 blocks; 512 thr = 8 waves; MBLK=32 rows.
// R9/R12 geometry (wave w owns cols [16w,16w+16) x all 4 gates; in-register
// gating; one barrier) + 1-kk-ahead B prefetch PINNED with
// __builtin_amdgcn_sched_barrier(0): the fence forbids the scheduler from
// sinking the prefetch loads to their uses (which is what erased R12's
// pipeline, VGPR_Count=64). MFMA cluster wrapped in s_setprio (T5).
// Budget: acc 32 + Bcur 32 + Bnext 32 + A 16 + addr ~12 ~= 125 <= 128
// (launch_bounds(512,4)) -> 2 blocks/CU.
// ---------------------------------------------------------------------------
__global__ __launch_bounds__(512, 4) void slstm_main(
    const float* __restrict__ x,     const float* __restrict__ hprev,
    const float* __restrict__ cprev, const float* __restrict__ nprev,
    const float* __restrict__ bi,    const float* __restrict__ bfg,
    const float* __restrict__ bo,    const float* __restrict__ bz,
    const ushort* __restrict__ whi,  const ushort* __restrict__ wlo,
    float* __restrict__ out)
{
    __shared__ ushort Ahi[32 * 256];   // 16 KB, swizzled bf16-hi of [x|h]
    __shared__ ushort Alo[32 * 256];   // 16 KB, swizzled bf16-lo
    char* AhiB = reinterpret_cast<char*>(Ahi);
    char* AloB = reinterpret_cast<char*>(Alo);

    const int tid  = threadIdx.x;
    const int row0 = blockIdx.x * MBLK;

    // ---- stage A: fp32 loads, truncation split to bf16 hi+lo, swizzled LDS
    #pragma unroll
    for (int i = 0; i < 2; ++i) {
        int f4  = tid + i * 512;          // 0..1023
        int row = f4 >> 5;                // 0..31
        int c4  = f4 & 31;
        f32x4 vx = reinterpret_cast<const f32x4*>(x)[(size_t)(row0 + row) * 32 + c4];
        f32x4 vh = reinterpret_cast<const f32x4*>(hprev)[(size_t)(row0 + row) * 32 + c4];
        #pragma unroll
        for (int half = 0; half < 2; ++half) {
            f32x4 v = half ? vh : vx;
            int kbase = half * 128 + 4 * c4;
            int q   = kbase >> 3;
            int sub = (kbase & 7) * 2;
            int byt = row * 512 + ((q ^ (row & 7)) << 4) + sub;
            uint a[4], rb[4];
            #pragma unroll
            for (int e = 0; e < 4; ++e) {
                a[e] = __builtin_bit_cast(uint, (float)v[e]);
                float hiF = __builtin_bit_cast(float, a[e] & 0xFFFF0000u);
                float r   = (float)v[e] - hiF;    // exact
                rb[e] = __builtin_bit_cast(uint, r);
            }
            uint2 hp, lp;
            hp.x = (a[0] >> 16)  | (a[1]  & 0xFFFF0000u);
            hp.y = (a[2] >> 16)  | (a[3]  & 0xFFFF0000u);
            lp.x = (rb[0] >> 16) | (rb[1] & 0xFFFF0000u);
            lp.y = (rb[2] >> 16) | (rb[3] & 0xFFFF0000u);
            *reinterpret_cast<uint2*>(AhiB + byt) = hp;
            *reinterpret_cast<uint2*>(AloB + byt) = lp;
        }
    }
    __syncthreads();   // the ONLY barrier

    const int w    = tid >> 6;         // wave id = column group
    const int lane = tid & 63;
    const int l15  = lane & 15;
    const int lg   = lane >> 4;

    // wave-constant B base (this wave's 16-col slice, all gates)
    const ushort* whiW = whi + (size_t)(w * 32) * 512 + lane * 8;
    const ushort* wloW = wlo + (size_t)(w * 32) * 512 + lane * 8;

    // ---- K-loop: 3-term split MFMA; 1-kk-ahead B prefetch, PINNED ----
    f32x4 acc[4][2] = {};

    bf16x8 cbh[4], cbl[4];             // current kk's B fragments
    #pragma unroll
    for (int g = 0; g < 4; ++g) {
        cbh[g] = *reinterpret_cast<const bf16x8*>(whiW + (g * 8 + 0) * 512);
        cbl[g] = *reinterpret_cast<const bf16x8*>(wloW + (g * 8 + 0) * 512);
    }

    #pragma unroll
    for (int kk = 0; kk < 8; ++kk) {
        // prefetch next kk's B first (earliest issue)
        bf16x8 nbh[4], nbl[4];
        {
            int nk = (kk + 1) & 7;
            #pragma unroll
            for (int g = 0; g < 4; ++g) {
                nbh[g] = *reinterpret_cast<const bf16x8*>(whiW + (g * 8 + nk) * 512);
                nbl[g] = *reinterpret_cast<const bf16x8*>(wloW + (g * 8 + nk) * 512);
            }
        }
        // this kk's A fragments from LDS
        bf16x8 ah[2], al[2];
        #pragma unroll
        for (int mi = 0; mi < 2; ++mi) {
            int row = mi * 16 + l15;
            int q   = kk * 4 + lg;
            int byt = row * 512 + ((q ^ (row & 7)) << 4);
            ah[mi] = *reinterpret_cast<const bf16x8*>(AhiB + byt);
            al[mi] = *reinterpret_cast<const bf16x8*>(AloB + byt);
        }
        // HARD FENCE: loads above may not sink below; MFMAs below may not
        // hoist above. This is what R12 was missing.
        __builtin_amdgcn_sched_barrier(0);

        __builtin_amdgcn_s_setprio(1);
        #pragma unroll
        for (int g = 0; g < 4; ++g) {
            #pragma unroll
            for (int mi = 0; mi < 2; ++mi)
                acc[g][mi] = __builtin_amdgcn_mfma_f32_16x16x32_bf16(ah[mi], cbh[g], acc[g][mi], 0, 0, 0);
            #pragma unroll
            for (int mi = 0; mi < 2; ++mi)
                acc[g][mi] = __builtin_amdgcn_mfma_f32_16x16x32_bf16(ah[mi], cbl[g], acc[g][mi], 0, 0, 0);
            #pragma unroll
            for (int mi = 0; mi < 2; ++mi)
                acc[g][mi] = __builtin_amdgcn_mfma_f32_16x16x32_bf16(al[mi], cbh[g], acc[g][mi], 0, 0, 0);
        }
        __builtin_amdgcn_s_setprio(0);
        __builtin_amdgcn_sched_barrier(0);

        // rotate (SSA rename, no real moves)
        #pragma unroll
        for (int g = 0; g < 4; ++g) { cbh[g] = nbh[g]; cbl[g] = nbl[g]; }
    }

    // ---- fully in-register epilogue ----
    const size_t OUTS = (size_t)NROWS * 128;
    const int c = w * 16 + l15;
    const float bic = bi[c], bfc = bfg[c], boc = bo[c], bzc = bz[c];
    const float* cB = cprev + (size_t)row0 * 128 + c;
    const float* nB = nprev + (size_t)row0 * 128 + c;
    float* outB = out + (size_t)row0 * 128 + c;

    float cpv[2][4], npv[2][4];
    #pragma unroll
    for (int mi = 0; mi < 2; ++mi)
        #pragma unroll
        for (int r = 0; r < 4; ++r) {
            int off = (mi * 16 + lg * 4 + r) * 128;
            cpv[mi][r] = cB[off];
            npv[mi][r] = nB[off];
        }

    #pragma unroll
    for (int mi = 0; mi < 2; ++mi)
        #pragma unroll
        for (int r = 0; r < 4; ++r) {
            float pit = acc[0][mi][r] + bic;
            float pft = acc[1][mi][r] + bfc;
            float pot = acc[2][mi][r] + boc;
            float pzt = acc[3][mi][r] + bzc;
            float m   = fmaxf(pft, pit);
            float i_t = __expf(pit - m);
            float f_t = __builtin_amdgcn_rcpf(1.0f + __expf(-pft)) + __expf(pft - m);
            float o_t = __builtin_amdgcn_rcpf(1.0f + __expf(-pot));
            float zc  = fminf(fmaxf(pzt, -15.0f), 15.0f);
            float e2  = __expf(2.0f * zc);
            float z_t = (e2 - 1.0f) * __builtin_amdgcn_rcpf(e2 + 1.0f);
            float c_t = f_t * cpv[mi][r] + i_t * z_t;
            float n_t = f_t * npv[mi][r] + i_t;
            float h_t = o_t * c_t * __builtin_amdgcn_rcpf(n_t + 1e-8f);
            int off = (mi * 16 + lg * 4 + r) * 128;
            outB[off]            = h_t;
            outB[OUTS + off]     = c_t;
            outB[2 * OUTS + off] = n_t;
        }
}

extern "C" void kernel_launch(void* const* d_in, const int* in_sizes, int n_in,
                              void* d_out, int out_size, void* d_ws, size_t ws_size,
                              hipStream_t stream) {
    const float* x  = (const float*)d_in[0];
    const float* h  = (const float*)d_in[1];
    const float* cp = (const float*)d_in[2];
    const float* np = (const float*)d_in[3];
    const float* Wi = (const float*)d_in[4];
    const float* Ui = (const float*)d_in[5];
    const float* Wf = (const float*)d_in[6];
    const float* Uf = (const float*)d_in[7];
    const float* Wo = (const float*)d_in[8];
    const float* Uo = (const float*)d_in[9];
    const float* Wz = (const float*)d_in[10];
    const float* Uz = (const float*)d_in[11];
    const float* bi = (const float*)d_in[12];
    const float* bf = (const float*)d_in[13];
    const float* bo = (const float*)d_in[14];
    const float* bz = (const float*)d_in[15];

    ushort* whi = (ushort*)d_ws;                  // 256 KB
    ushort* wlo = whi + 4 * 128 * 256;            // 256 KB

    prep_weights<<<512, 256, 0, stream>>>(Wi, Ui, Wf, Uf, Wo, Uo, Wz, Uz, whi, wlo);
    slstm_main<<<NBLKS, 512, 0, stream>>>(x, h, cp, np, bi, bf, bo, bz, whi, wlo,
                                          (float*)d_out);
}

// Round 14
// 446.227 us; speedup vs baseline: 1.2828x; 1.2828x over previous
//
#include <hip/hip_runtime.h>
#include <hip/hip_bf16.h>

typedef __attribute__((ext_vector_type(8))) short bf16x8;
typedef __attribute__((ext_vector_type(4))) float f32x4;

#define NROWS 262144
#define MBLK  32
#define NBLKS (NROWS / MBLK)   /* 8192 */

// ---------------------------------------------------------------------------
// Weight prep (layout identical to R9): B-fragment keyed by (w,g,kk):
//   elem (w,g,kk,lane,j) = Wbig[g][n = w*16 + (lane&15)]
//                                [k = kk*32 + (lane>>4)*8 + j]
//   at offset ((w*32 + g*8 + kk)*64 + lane)*8 + j.  RNE hi/lo split.
// ---------------------------------------------------------------------------
__global__ void prep_weights(
    const float* __restrict__ Wi, const float* __restrict__ Ui,
    const float* __restrict__ Wf, const float* __restrict__ Uf,
    const float* __restrict__ Wo, const float* __restrict__ Uo,
    const float* __restrict__ Wz, const float* __restrict__ Uz,
    ushort* __restrict__ hi, ushort* __restrict__ lo)
{
    int idx = blockIdx.x * 256 + threadIdx.x;   // 0..131071
    int j    = idx & 7;
    int lane = (idx >> 3) & 63;
    int kk   = (idx >> 9) & 7;
    int g    = (idx >> 12) & 3;
    int w    = (idx >> 14) & 7;
    int n = w * 16 + (lane & 15);
    int k = kk * 32 + (lane >> 4) * 8 + j;
    const float* W; const float* U;
    if (g == 0)      { W = Wi; U = Ui; }
    else if (g == 1) { W = Wf; U = Uf; }
    else if (g == 2) { W = Wo; U = Uo; }
    else             { W = Wz; U = Uz; }
    float v = (k < 128) ? W[n * 128 + k] : U[n * 128 + (k - 128)];
    __hip_bfloat16 hb = __float2bfloat16(v);
    float r = v - __bfloat162float(hb);
    __hip_bfloat16 lb = __float2bfloat16(r);
    hi[idx] = *reinterpret_cast<ushort*>(&hb);
    lo[idx] = *reinterpret_cast<ushort*>(&lb);
}

// ---------------------------------------------------------------------------
// Main fused kernel. 8192 blocks; 512 thr = 8 waves; MBLK=32 rows.
// R9 geometry: wave w owns cols [16w,16w+16) x ALL 4 gates; in-register
// gating; ONE barrier; LDS 32 KB. Two concurrency changes vs R9:
//   (1) launch_bounds(512,6): unified cap 85 (arch 48 + acc 32 = 80 fits)
//       -> 3 blocks/CU = 6 waves/SIMD (was 4).
//   (2) per-wave kk STAGGER (kka = (kk+w)&7): waves traverse K in rotated
//       order so B-load bursts and MFMA bursts desynchronize across waves
//       instead of aligning (the ~25% MfmaUtil plateau cause).
// ---------------------------------------------------------------------------
__global__ __launch_bounds__(512, 6) void slstm_main(
    const float* __restrict__ x,     const float* __restrict__ hprev,
    const float* __restrict__ cprev, const float* __restrict__ nprev,
    const float* __restrict__ bi,    const float* __restrict__ bfg,
    const float* __restrict__ bo,    const float* __restrict__ bz,
    const ushort* __restrict__ whi,  const ushort* __restrict__ wlo,
    float* __restrict__ out)
{
    __shared__ ushort Ahi[32 * 256];   // 16 KB, swizzled bf16-hi of [x|h]
    __shared__ ushort Alo[32 * 256];   // 16 KB, swizzled bf16-lo
    char* AhiB = reinterpret_cast<char*>(Ahi);
    char* AloB = reinterpret_cast<char*>(Alo);

    const int tid  = threadIdx.x;
    const int row0 = blockIdx.x * MBLK;

    // ---- stage A: fp32 loads, truncation split to bf16 hi+lo, swizzled LDS
    #pragma unroll
    for (int i = 0; i < 2; ++i) {
        int f4  = tid + i * 512;          // 0..1023
        int row = f4 >> 5;                // 0..31
        int c4  = f4 & 31;
        f32x4 vx = reinterpret_cast<const f32x4*>(x)[(size_t)(row0 + row) * 32 + c4];
        f32x4 vh = reinterpret_cast<const f32x4*>(hprev)[(size_t)(row0 + row) * 32 + c4];
        #pragma unroll
        for (int half = 0; half < 2; ++half) {
            f32x4 v = half ? vh : vx;
            int kbase = half * 128 + 4 * c4;
            int q   = kbase >> 3;
            int sub = (kbase & 7) * 2;
            int byt = row * 512 + ((q ^ (row & 7)) << 4) + sub;
            uint a[4], rb[4];
            #pragma unroll
            for (int e = 0; e < 4; ++e) {
                a[e] = __builtin_bit_cast(uint, (float)v[e]);
                float hiF = __builtin_bit_cast(float, a[e] & 0xFFFF0000u);
                float r   = (float)v[e] - hiF;    // exact
                rb[e] = __builtin_bit_cast(uint, r);
            }
            uint2 hp, lp;
            hp.x = (a[0] >> 16)  | (a[1]  & 0xFFFF0000u);
            hp.y = (a[2] >> 16)  | (a[3]  & 0xFFFF0000u);
            lp.x = (rb[0] >> 16) | (rb[1] & 0xFFFF0000u);
            lp.y = (rb[2] >> 16) | (rb[3] & 0xFFFF0000u);
            *reinterpret_cast<uint2*>(AhiB + byt) = hp;
            *reinterpret_cast<uint2*>(AloB + byt) = lp;
        }
    }
    __syncthreads();   // the ONLY barrier

    const int w    = tid >> 6;         // wave id = column group
    const int lane = tid & 63;
    const int l15  = lane & 15;
    const int lg   = lane >> 4;

    // wave-constant B base (this wave's 16-col slice, all gates)
    const ushort* whiW = whi + (size_t)(w * 32) * 512 + lane * 8;
    const ushort* wloW = wlo + (size_t)(w * 32) * 512 + lane * 8;

    // ---- K-loop: 3-term split MFMA, per-wave staggered kk order ----
    f32x4 acc[4][2] = {};

    #pragma unroll
    for (int kk = 0; kk < 8; ++kk) {
        const int kka = (kk + w) & 7;   // wave-rotated K order (desync)
        bf16x8 ah[2], al[2];
        #pragma unroll
        for (int mi = 0; mi < 2; ++mi) {
            int row = mi * 16 + l15;
            int q   = kka * 4 + lg;
            int byt = row * 512 + ((q ^ (row & 7)) << 4);
            ah[mi] = *reinterpret_cast<const bf16x8*>(AhiB + byt);
            al[mi] = *reinterpret_cast<const bf16x8*>(AloB + byt);
        }
        #pragma unroll
        for (int g = 0; g < 4; ++g) {
            int eoff = (g * 8 + kka) * 512;
            bf16x8 bh = *reinterpret_cast<const bf16x8*>(whiW + eoff);
            bf16x8 bl = *reinterpret_cast<const bf16x8*>(wloW + eoff);
            #pragma unroll
            for (int mi = 0; mi < 2; ++mi)
                acc[g][mi] = __builtin_amdgcn_mfma_f32_16x16x32_bf16(ah[mi], bh, acc[g][mi], 0, 0, 0);
            #pragma unroll
            for (int mi = 0; mi < 2; ++mi)
                acc[g][mi] = __builtin_amdgcn_mfma_f32_16x16x32_bf16(ah[mi], bl, acc[g][mi], 0, 0, 0);
            #pragma unroll
            for (int mi = 0; mi < 2; ++mi)
                acc[g][mi] = __builtin_amdgcn_mfma_f32_16x16x32_bf16(al[mi], bh, acc[g][mi], 0, 0, 0);
        }
    }

    // ---- fully in-register epilogue ----
    const size_t OUTS = (size_t)NROWS * 128;
    const int c = w * 16 + l15;
    const float bic = bi[c], bfc = bfg[c], boc = bo[c], bzc = bz[c];
    const float* cB = cprev + (size_t)row0 * 128 + c;
    const float* nB = nprev + (size_t)row0 * 128 + c;
    float* outB = out + (size_t)row0 * 128 + c;

    float cpv[2][4], npv[2][4];
    #pragma unroll
    for (int mi = 0; mi < 2; ++mi)
        #pragma unroll
        for (int r = 0; r < 4; ++r) {
            int off = (mi * 16 + lg * 4 + r) * 128;
            cpv[mi][r] = cB[off];
            npv[mi][r] = nB[off];
        }

    #pragma unroll
    for (int mi = 0; mi < 2; ++mi)
        #pragma unroll
        for (int r = 0; r < 4; ++r) {
            float pit = acc[0][mi][r] + bic;
            float pft = acc[1][mi][r] + bfc;
            float pot = acc[2][mi][r] + boc;
            float pzt = acc[3][mi][r] + bzc;
            float m   = fmaxf(pft, pit);
            float i_t = __expf(pit - m);
            float f_t = __builtin_amdgcn_rcpf(1.0f + __expf(-pft)) + __expf(pft - m);
            float o_t = __builtin_amdgcn_rcpf(1.0f + __expf(-pot));
            float zc  = fminf(fmaxf(pzt, -15.0f), 15.0f);
            float e2  = __expf(2.0f * zc);
            float z_t = (e2 - 1.0f) * __builtin_amdgcn_rcpf(e2 + 1.0f);
            float c_t = f_t * cpv[mi][r] + i_t * z_t;
            float n_t = f_t * npv[mi][r] + i_t;
            float h_t = o_t * c_t * __builtin_amdgcn_rcpf(n_t + 1e-8f);
            int off = (mi * 16 + lg * 4 + r) * 128;
            outB[off]            = h_t;
            outB[OUTS + off]     = c_t;
            outB[2 * OUTS + off] = n_t;
        }
}

extern "C" void kernel_launch(void* const* d_in, const int* in_sizes, int n_in,
                              void* d_out, int out_size, void* d_ws, size_t ws_size,
                              hipStream_t stream) {
    const float* x  = (const float*)d_in[0];
    const float* h  = (const float*)d_in[1];
    const float* cp = (const float*)d_in[2];
    const float* np = (const float*)d_in[3];
    const float* Wi = (const float*)d_in[4];
    const float* Ui = (const float*)d_in[5];
    const float* Wf = (const float*)d_in[6];
    const float* Uf = (const float*)d_in[7];
    const float* Wo = (const float*)d_in[8];
    const float* Uo = (const float*)d_in[9];
    const float* Wz = (const float*)d_in[10];
    const float* Uz = (const float*)d_in[11];
    const float* bi = (const float*)d_in[12];
    const float* bf = (const float*)d_in[13];
    const float* bo = (const float*)d_in[14];
    const float* bz = (const float*)d_in[15];

    ushort* whi = (ushort*)d_ws;                  // 256 KB
    ushort* wlo = whi + 4 * 128 * 256;            // 256 KB

    prep_weights<<<512, 256, 0, stream>>>(Wi, Ui, Wf, Uf, Wo, Uo, Wz, Uz, whi, wlo);
    slstm_main<<<NBLKS, 512, 0, stream>>>(x, h, cp, np, bi, bf, bo, bz, whi, wlo,
                                          (float*)d_out);
}

// Round 15
// 272.570 us; speedup vs baseline: 2.1001x; 1.6371x over previous
//
#include <hip/hip_runtime.h>
#include <hip/hip_bf16.h>

typedef __attribute__((ext_vector_type(8))) _Float16 f16x8;
typedef __attribute__((ext_vector_type(4))) float f32x4;

#define NROWS 262144
#define MBLK  32
#define NBLKS (NROWS / MBLK)   /* 8192 */

// ---------------------------------------------------------------------------
// Weight prep: SINGLE fp16 B-fragment buffer (layout as R9), keyed (w,g,kk):
//   elem (w,g,kk,lane,j) = Wbig[g][n = w*16 + (lane&15)]
//                                [k = kk*32 + (lane>>4)*8 + j]
//   at offset ((w*32 + g*8 + kk)*64 + lane)*8 + j.
// fp16 RNE: weight error 2^-11 rel -> preact error ~2.8e-4 rel, at the
// fast-math gating noise floor. No lo matrix needed.
// ---------------------------------------------------------------------------
__global__ void prep_weights(
    const float* __restrict__ Wi, const float* __restrict__ Ui,
    const float* __restrict__ Wf, const float* __restrict__ Uf,
    const float* __restrict__ Wo, const float* __restrict__ Uo,
    const float* __restrict__ Wz, const float* __restrict__ Uz,
    ushort* __restrict__ wh)
{
    int idx = blockIdx.x * 256 + threadIdx.x;   // 0..131071
    int j    = idx & 7;
    int lane = (idx >> 3) & 63;
    int kk   = (idx >> 9) & 7;
    int g    = (idx >> 12) & 3;
    int w    = (idx >> 14) & 7;
    int n = w * 16 + (lane & 15);
    int k = kk * 32 + (lane >> 4) * 8 + j;
    const float* W; const float* U;
    if (g == 0)      { W = Wi; U = Ui; }
    else if (g == 1) { W = Wf; U = Uf; }
    else if (g == 2) { W = Wo; U = Uo; }
    else             { W = Wz; U = Uz; }
    float v = (k < 128) ? W[n * 128 + k] : U[n * 128 + (k - 128)];
    _Float16 hh = (_Float16)v;                  // RNE
    wh[idx] = __builtin_bit_cast(ushort, hh);
}

// ---------------------------------------------------------------------------
// Main fused kernel. 8192 blocks; 512 thr = 8 waves; MBLK=32 rows.
// R9 chassis: wave w owns cols [16w,16w+16) x ALL 4 gates; in-register
// gating; ONE barrier; LDS 32 KB; launch_bounds(512,4) (2 blocks/CU, no
// spills). Numerics: A split EXACTLY as fp16 ah + fp16 al (residual 2^-22);
// B single fp16. acc = (ah + al) @ B via 2 MFMAs per (gate,kk) -- 2/3 the
// MFMA work and half the B-traffic of the bf16 3-term scheme.
// ---------------------------------------------------------------------------
__global__ __launch_bounds__(512, 4) void slstm_main(
    const float* __restrict__ x,     const float* __restrict__ hprev,
    const float* __restrict__ cprev, const float* __restrict__ nprev,
    const float* __restrict__ bi,    const float* __restrict__ bfg,
    const float* __restrict__ bo,    const float* __restrict__ bz,
    const ushort* __restrict__ wh,
    float* __restrict__ out)
{
    __shared__ ushort Ahi[32 * 256];   // 16 KB, swizzled fp16-hi of [x|h]
    __shared__ ushort Alo[32 * 256];   // 16 KB, swizzled fp16-lo
    char* AhiB = reinterpret_cast<char*>(Ahi);
    char* AloB = reinterpret_cast<char*>(Alo);

    const int tid  = threadIdx.x;
    const int row0 = blockIdx.x * MBLK;

    // ---- stage A: fp32 loads, exact fp16 hi+lo split, swizzled LDS ----
    #pragma unroll
    for (int i = 0; i < 2; ++i) {
        int f4  = tid + i * 512;          // 0..1023
        int row = f4 >> 5;                // 0..31
        int c4  = f4 & 31;
        f32x4 vx = reinterpret_cast<const f32x4*>(x)[(size_t)(row0 + row) * 32 + c4];
        f32x4 vh = reinterpret_cast<const f32x4*>(hprev)[(size_t)(row0 + row) * 32 + c4];
        #pragma unroll
        for (int half = 0; half < 2; ++half) {
            f32x4 v = half ? vh : vx;
            int kbase = half * 128 + 4 * c4;
            int q   = kbase >> 3;
            int sub = (kbase & 7) * 2;
            int byt = row * 512 + ((q ^ (row & 7)) << 4) + sub;
            ushort hb[4], lb[4];
            #pragma unroll
            for (int e = 0; e < 4; ++e) {
                float ve = v[e];
                _Float16 hh = (_Float16)ve;           // RNE
                _Float16 hl = (_Float16)(ve - (float)hh);
                hb[e] = __builtin_bit_cast(ushort, hh);
                lb[e] = __builtin_bit_cast(ushort, hl);
            }
            uint2 hp, lp;
            hp.x = (uint)hb[0] | ((uint)hb[1] << 16);
            hp.y = (uint)hb[2] | ((uint)hb[3] << 16);
            lp.x = (uint)lb[0] | ((uint)lb[1] << 16);
            lp.y = (uint)lb[2] | ((uint)lb[3] << 16);
            *reinterpret_cast<uint2*>(AhiB + byt) = hp;
            *reinterpret_cast<uint2*>(AloB + byt) = lp;
        }
    }
    __syncthreads();   // the ONLY barrier

    const int w    = tid >> 6;         // wave id = column group
    const int lane = tid & 63;
    const int l15  = lane & 15;
    const int lg   = lane >> 4;

    // wave-constant B base (this wave's 16-col slice, all gates)
    const ushort* whW = wh + (size_t)(w * 32) * 512 + lane * 8;

    // ---- K-loop: 2-term fp16 MFMA; acc[gate][mi] ----
    f32x4 acc[4][2] = {};

    #pragma unroll
    for (int kk = 0; kk < 8; ++kk) {
        f16x8 ah[2], al[2];
        #pragma unroll
        for (int mi = 0; mi < 2; ++mi) {
            int row = mi * 16 + l15;
            int q   = kk * 4 + lg;
            int byt = row * 512 + ((q ^ (row & 7)) << 4);
            ah[mi] = *reinterpret_cast<const f16x8*>(AhiB + byt);
            al[mi] = *reinterpret_cast<const f16x8*>(AloB + byt);
        }
        #pragma unroll
        for (int g = 0; g < 4; ++g) {
            f16x8 b = *reinterpret_cast<const f16x8*>(whW + (g * 8 + kk) * 512);
            #pragma unroll
            for (int mi = 0; mi < 2; ++mi)
                acc[g][mi] = __builtin_amdgcn_mfma_f32_16x16x32_f16(ah[mi], b, acc[g][mi], 0, 0, 0);
            #pragma unroll
            for (int mi = 0; mi < 2; ++mi)
                acc[g][mi] = __builtin_amdgcn_mfma_f32_16x16x32_f16(al[mi], b, acc[g][mi], 0, 0, 0);
        }
    }

    // ---- fully in-register epilogue ----
    const size_t OUTS = (size_t)NROWS * 128;
    const int c = w * 16 + l15;
    const float bic = bi[c], bfc = bfg[c], boc = bo[c], bzc = bz[c];
    const float* cB = cprev + (size_t)row0 * 128 + c;
    const float* nB = nprev + (size_t)row0 * 128 + c;
    float* outB = out + (size_t)row0 * 128 + c;

    float cpv[2][4], npv[2][4];
    #pragma unroll
    for (int mi = 0; mi < 2; ++mi)
        #pragma unroll
        for (int r = 0; r < 4; ++r) {
            int off = (mi * 16 + lg * 4 + r) * 128;
            cpv[mi][r] = cB[off];
            npv[mi][r] = nB[off];
        }

    #pragma unroll
    for (int mi = 0; mi < 2; ++mi)
        #pragma unroll
        for (int r = 0; r < 4; ++r) {
            float pit = acc[0][mi][r] + bic;
            float pft = acc[1][mi][r] + bfc;
            float pot = acc[2][mi][r] + boc;
            float pzt = acc[3][mi][r] + bzc;
            float m   = fmaxf(pft, pit);
            float i_t = __expf(pit - m);
            float f_t = __builtin_amdgcn_rcpf(1.0f + __expf(-pft)) + __expf(pft - m);
            float o_t = __builtin_amdgcn_rcpf(1.0f + __expf(-pot));
            float zc  = fminf(fmaxf(pzt, -15.0f), 15.0f);
            float e2  = __expf(2.0f * zc);
            float z_t = (e2 - 1.0f) * __builtin_amdgcn_rcpf(e2 + 1.0f);
            float c_t = f_t * cpv[mi][r] + i_t * z_t;
            float n_t = f_t * npv[mi][r] + i_t;
            float h_t = o_t * c_t * __builtin_amdgcn_rcpf(n_t + 1e-8f);
            int off = (mi * 16 + lg * 4 + r) * 128;
            outB[off]            = h_t;
            outB[OUTS + off]     = c_t;
            outB[2 * OUTS + off] = n_t;
        }
}

extern "C" void kernel_launch(void* const* d_in, const int* in_sizes, int n_in,
                              void* d_out, int out_size, void* d_ws, size_t ws_size,
                              hipStream_t stream) {
    const float* x  = (const float*)d_in[0];
    const float* h  = (const float*)d_in[1];
    const float* cp = (const float*)d_in[2];
    const float* np = (const float*)d_in[3];
    const float* Wi = (const float*)d_in[4];
    const float* Ui = (const float*)d_in[5];
    const float* Wf = (const float*)d_in[6];
    const float* Uf = (const float*)d_in[7];
    const float* Wo = (const float*)d_in[8];
    const float* Uo = (const float*)d_in[9];
    const float* Wz = (const float*)d_in[10];
    const float* Uz = (const float*)d_in[11];
    const float* bi = (const float*)d_in[12];
    const float* bf = (const float*)d_in[13];
    const float* bo = (const float*)d_in[14];
    const float* bz = (const float*)d_in[15];

    ushort* wh = (ushort*)d_ws;                   // 256 KB fp16 fragments

    prep_weights<<<512, 256, 0, stream>>>(Wi, Ui, Wf, Uf, Wo, Uo, Wz, Uz, wh);
    slstm_main<<<NBLKS, 512, 0, stream>>>(x, h, cp, np, bi, bf, bo, bz, wh,
                                          (float*)d_out);
}

// Round 16
// 265.895 us; speedup vs baseline: 2.1529x; 1.0251x over previous
//
#include <hip/hip_runtime.h>
#include <hip/hip_bf16.h>

typedef __attribute__((ext_vector_type(8))) _Float16 f16x8;
typedef __attribute__((ext_vector_type(4))) float f32x4;

#define NROWS 262144
#define MBLK  64
#define NBLKS (NROWS / MBLK)   /* 4096 */

// ---------------------------------------------------------------------------
// Weight prep: SINGLE fp16 B-fragment buffer, keyed (w,g,kk):
//   elem (w,g,kk,lane,j) = Wbig[g][n = w*16 + (lane&15)]
//                                [k = kk*32 + (lane>>4)*8 + j]
//   at offset ((w*32 + g*8 + kk)*64 + lane)*8 + j.
// ---------------------------------------------------------------------------
__global__ void prep_weights(
    const float* __restrict__ Wi, const float* __restrict__ Ui,
    const float* __restrict__ Wf, const float* __restrict__ Uf,
    const float* __restrict__ Wo, const float* __restrict__ Uo,
    const float* __restrict__ Wz, const float* __restrict__ Uz,
    ushort* __restrict__ wh)
{
    int idx = blockIdx.x * 256 + threadIdx.x;   // 0..131071
    int j    = idx & 7;
    int lane = (idx >> 3) & 63;
    int kk   = (idx >> 9) & 7;
    int g    = (idx >> 12) & 3;
    int w    = (idx >> 14) & 7;
    int n = w * 16 + (lane & 15);
    int k = kk * 32 + (lane >> 4) * 8 + j;
    const float* W; const float* U;
    if (g == 0)      { W = Wi; U = Ui; }
    else if (g == 1) { W = Wf; U = Uf; }
    else if (g == 2) { W = Wo; U = Uo; }
    else             { W = Wz; U = Uz; }
    float v = (k < 128) ? W[n * 128 + k] : U[n * 128 + (k - 128)];
    _Float16 hh = (_Float16)v;                  // RNE
    wh[idx] = __builtin_bit_cast(ushort, hh);
}

// ---------------------------------------------------------------------------
// Main fused kernel. 4096 blocks; 512 thr = 8 waves; MBLK=64 rows.
// Wave w owns cols [16w,16w+16) x ALL 4 gates x 64 rows: acc[4][4]=64 regs,
// in-register gating, ONE barrier. Single-term fp16 A + fp16 B:
//   - 8 MFMAs per kk... 4 B-loads, 4 A ds_reads, 16 MFMAs per kk per wave
//   - B L2-traffic 1.05 GB (each fragment serves 64 rows)
//   - stage has no hi/lo split (one cvt per element), LDS = 32 KB
// Error budget: A,B both fp16 RNE -> ~7e-4 rel preact error; observed
// absmax should be ~8*sqrt(2) ~= 12 vs threshold 69.
// ---------------------------------------------------------------------------
__global__ __launch_bounds__(512, 4) void slstm_main(
    const float* __restrict__ x,     const float* __restrict__ hprev,
    const float* __restrict__ cprev, const float* __restrict__ nprev,
    const float* __restrict__ bi,    const float* __restrict__ bfg,
    const float* __restrict__ bo,    const float* __restrict__ bz,
    const ushort* __restrict__ wh,
    float* __restrict__ out)
{
    __shared__ ushort A[64 * 256];   // 32 KB, swizzled fp16 of [x|h]
    char* AB = reinterpret_cast<char*>(A);

    const int tid  = threadIdx.x;
    const int row0 = blockIdx.x * MBLK;

    // ---- stage A: fp32 loads -> fp16 RNE, swizzled LDS ----
    #pragma unroll
    for (int i = 0; i < 4; ++i) {
        int f4  = tid + i * 512;          // 0..2047
        int row = f4 >> 5;                // 0..63
        int c4  = f4 & 31;
        f32x4 vx = reinterpret_cast<const f32x4*>(x)[(size_t)(row0 + row) * 32 + c4];
        f32x4 vh = reinterpret_cast<const f32x4*>(hprev)[(size_t)(row0 + row) * 32 + c4];
        #pragma unroll
        for (int half = 0; half < 2; ++half) {
            f32x4 v = half ? vh : vx;
            int kbase = half * 128 + 4 * c4;
            int q   = kbase >> 3;
            int sub = (kbase & 7) * 2;
            int byt = row * 512 + ((q ^ (row & 7)) << 4) + sub;
            ushort hb[4];
            #pragma unroll
            for (int e = 0; e < 4; ++e) {
                _Float16 hh = (_Float16)(float)v[e];   // RNE
                hb[e] = __builtin_bit_cast(ushort, hh);
            }
            uint2 hp;
            hp.x = (uint)hb[0] | ((uint)hb[1] << 16);
            hp.y = (uint)hb[2] | ((uint)hb[3] << 16);
            *reinterpret_cast<uint2*>(AB + byt) = hp;
        }
    }
    __syncthreads();   // the ONLY barrier

    const int w    = tid >> 6;         // wave id = column group
    const int lane = tid & 63;
    const int l15  = lane & 15;
    const int lg   = lane >> 4;

    // wave-constant B base (this wave's 16-col slice, all gates)
    const ushort* whW = wh + (size_t)(w * 32) * 512 + lane * 8;

    // ---- K-loop: single-term fp16 MFMA; acc[gate][mi] ----
    f32x4 acc[4][4] = {};

    #pragma unroll
    for (int kk = 0; kk < 8; ++kk) {
        f16x8 ah[4];
        #pragma unroll
        for (int mi = 0; mi < 4; ++mi) {
            int row = mi * 16 + l15;
            int q   = kk * 4 + lg;
            int byt = row * 512 + ((q ^ (row & 7)) << 4);
            ah[mi] = *reinterpret_cast<const f16x8*>(AB + byt);
        }
        #pragma unroll
        for (int g = 0; g < 4; ++g) {
            f16x8 b = *reinterpret_cast<const f16x8*>(whW + (g * 8 + kk) * 512);
            #pragma unroll
            for (int mi = 0; mi < 4; ++mi)
                acc[g][mi] = __builtin_amdgcn_mfma_f32_16x16x32_f16(ah[mi], b, acc[g][mi], 0, 0, 0);
        }
    }

    // ---- fully in-register epilogue, 16 rows per group (JIT c/n) ----
    const size_t OUTS = (size_t)NROWS * 128;
    const int c = w * 16 + l15;
    const float bic = bi[c], bfc = bfg[c], boc = bo[c], bzc = bz[c];
    const float* cB = cprev + (size_t)row0 * 128 + c;
    const float* nB = nprev + (size_t)row0 * 128 + c;
    float* outB = out + (size_t)row0 * 128 + c;

    #pragma unroll
    for (int mi = 0; mi < 4; ++mi) {
        float cpv[4], npv[4];
        #pragma unroll
        for (int r = 0; r < 4; ++r) {
            int off = (mi * 16 + lg * 4 + r) * 128;
            cpv[r] = cB[off];
            npv[r] = nB[off];
        }
        #pragma unroll
        for (int r = 0; r < 4; ++r) {
            float pit = acc[0][mi][r] + bic;
            float pft = acc[1][mi][r] + bfc;
            float pot = acc[2][mi][r] + boc;
            float pzt = acc[3][mi][r] + bzc;
            float m   = fmaxf(pft, pit);
            float i_t = __expf(pit - m);
            float f_t = __builtin_amdgcn_rcpf(1.0f + __expf(-pft)) + __expf(pft - m);
            float o_t = __builtin_amdgcn_rcpf(1.0f + __expf(-pot));
            float zc  = fminf(fmaxf(pzt, -15.0f), 15.0f);
            float e2  = __expf(2.0f * zc);
            float z_t = (e2 - 1.0f) * __builtin_amdgcn_rcpf(e2 + 1.0f);
            float c_t = f_t * cpv[r] + i_t * z_t;
            float n_t = f_t * npv[r] + i_t;
            float h_t = o_t * c_t * __builtin_amdgcn_rcpf(n_t + 1e-8f);
            int off = (mi * 16 + lg * 4 + r) * 128;
            outB[off]            = h_t;
            outB[OUTS + off]     = c_t;
            outB[2 * OUTS + off] = n_t;
        }
    }
}

extern "C" void kernel_launch(void* const* d_in, const int* in_sizes, int n_in,
                              void* d_out, int out_size, void* d_ws, size_t ws_size,
                              hipStream_t stream) {
    const float* x  = (const float*)d_in[0];
    const float* h  = (const float*)d_in[1];
    const float* cp = (const float*)d_in[2];
    const float* np = (const float*)d_in[3];
    const float* Wi = (const float*)d_in[4];
    const float* Ui = (const float*)d_in[5];
    const float* Wf = (const float*)d_in[6];
    const float* Uf = (const float*)d_in[7];
    const float* Wo = (const float*)d_in[8];
    const float* Uo = (const float*)d_in[9];
    const float* Wz = (const float*)d_in[10];
    const float* Uz = (const float*)d_in[11];
    const float* bi = (const float*)d_in[12];
    const float* bf = (const float*)d_in[13];
    const float* bo = (const float*)d_in[14];
    const float* bz = (const float*)d_in[15];

    ushort* wh = (ushort*)d_ws;                   // 256 KB fp16 fragments

    prep_weights<<<512, 256, 0, stream>>>(Wi, Ui, Wf, Uf, Wo, Uo, Wz, Uz, wh);
    slstm_main<<<NBLKS, 512, 0, stream>>>(x, h, cp, np, bi, bf, bo, bz, wh,
                                          (float*)d_out);
}

// Round 17
// 251.569 us; speedup vs baseline: 2.2755x; 1.0569x over previous
//
#include <hip/hip_runtime.h>
#include <hip/hip_bf16.h>

typedef __attribute__((ext_vector_type(8))) _Float16 f16x8;
typedef __attribute__((ext_vector_type(4))) float f32x4;

#define NROWS 262144
#define MBLK  32
#define NBLKS (NROWS / MBLK)   /* 8192 */

// ---------------------------------------------------------------------------
// Weight prep: SINGLE fp16 B-fragment buffer, keyed (w,g,kk):
//   elem (w,g,kk,lane,j) = Wbig[g][n = w*16 + (lane&15)]
//                                [k = kk*32 + (lane>>4)*8 + j]
//   at offset ((w*32 + g*8 + kk)*64 + lane)*8 + j.
// ---------------------------------------------------------------------------
__global__ void prep_weights(
    const float* __restrict__ Wi, const float* __restrict__ Ui,
    const float* __restrict__ Wf, const float* __restrict__ Uf,
    const float* __restrict__ Wo, const float* __restrict__ Uo,
    const float* __restrict__ Wz, const float* __restrict__ Uz,
    ushort* __restrict__ wh)
{
    int idx = blockIdx.x * 256 + threadIdx.x;   // 0..131071
    int j    = idx & 7;
    int lane = (idx >> 3) & 63;
    int kk   = (idx >> 9) & 7;
    int g    = (idx >> 12) & 3;
    int w    = (idx >> 14) & 7;
    int n = w * 16 + (lane & 15);
    int k = kk * 32 + (lane >> 4) * 8 + j;
    const float* W; const float* U;
    if (g == 0)      { W = Wi; U = Ui; }
    else if (g == 1) { W = Wf; U = Uf; }
    else if (g == 2) { W = Wo; U = Uo; }
    else             { W = Wz; U = Uz; }
    float v = (k < 128) ? W[n * 128 + k] : U[n * 128 + (k - 128)];
    _Float16 hh = (_Float16)v;                  // RNE
    wh[idx] = __builtin_bit_cast(ushort, hh);
}

// ---------------------------------------------------------------------------
// Main fused kernel. 8192 blocks; 512 thr = 8 waves; MBLK=32 rows.
// Wave w owns cols [16w,16w+16) x ALL 4 gates x 32 rows: acc[4][2] = 32
// AGPRs; single-term fp16 A and B. Unified budget: acc 32 + arch ~46 ~= 78
// <= 85 cap from launch_bounds(512,6) -> 3 blocks/CU (6 waves/SIMD), the
// occupancy level acc[4][4]=64 made impossible. In-register gating, ONE
// barrier, LDS 16 KB.
// ---------------------------------------------------------------------------
__global__ __launch_bounds__(512, 6) void slstm_main(
    const float* __restrict__ x,     const float* __restrict__ hprev,
    const float* __restrict__ cprev, const float* __restrict__ nprev,
    const float* __restrict__ bi,    const float* __restrict__ bfg,
    const float* __restrict__ bo,    const float* __restrict__ bz,
    const ushort* __restrict__ wh,
    float* __restrict__ out)
{
    __shared__ ushort A[32 * 256];   // 16 KB, swizzled fp16 of [x|h]
    char* AB = reinterpret_cast<char*>(A);

    const int tid  = threadIdx.x;
    const int row0 = blockIdx.x * MBLK;

    // ---- stage A: fp32 loads -> fp16 RNE, swizzled LDS ----
    #pragma unroll
    for (int i = 0; i < 2; ++i) {
        int f4  = tid + i * 512;          // 0..1023
        int row = f4 >> 5;                // 0..31
        int c4  = f4 & 31;
        f32x4 vx = reinterpret_cast<const f32x4*>(x)[(size_t)(row0 + row) * 32 + c4];
        f32x4 vh = reinterpret_cast<const f32x4*>(hprev)[(size_t)(row0 + row) * 32 + c4];
        #pragma unroll
        for (int half = 0; half < 2; ++half) {
            f32x4 v = half ? vh : vx;
            int kbase = half * 128 + 4 * c4;
            int q   = kbase >> 3;
            int sub = (kbase & 7) * 2;
            int byt = row * 512 + ((q ^ (row & 7)) << 4) + sub;
            ushort hb[4];
            #pragma unroll
            for (int e = 0; e < 4; ++e) {
                _Float16 hh = (_Float16)(float)v[e];   // RNE
                hb[e] = __builtin_bit_cast(ushort, hh);
            }
            uint2 hp;
            hp.x = (uint)hb[0] | ((uint)hb[1] << 16);
            hp.y = (uint)hb[2] | ((uint)hb[3] << 16);
            *reinterpret_cast<uint2*>(AB + byt) = hp;
        }
    }
    __syncthreads();   // the ONLY barrier

    const int w    = tid >> 6;         // wave id = column group
    const int lane = tid & 63;
    const int l15  = lane & 15;
    const int lg   = lane >> 4;

    // wave-constant B base (this wave's 16-col slice, all gates)
    const ushort* whW = wh + (size_t)(w * 32) * 512 + lane * 8;

    // ---- K-loop: single-term fp16 MFMA; acc[gate][mi] ----
    f32x4 acc[4][2] = {};

    #pragma unroll
    for (int kk = 0; kk < 8; ++kk) {
        f16x8 ah[2];
        #pragma unroll
        for (int mi = 0; mi < 2; ++mi) {
            int row = mi * 16 + l15;
            int q   = kk * 4 + lg;
            int byt = row * 512 + ((q ^ (row & 7)) << 4);
            ah[mi] = *reinterpret_cast<const f16x8*>(AB + byt);
        }
        #pragma unroll
        for (int g = 0; g < 4; ++g) {
            f16x8 b = *reinterpret_cast<const f16x8*>(whW + (g * 8 + kk) * 512);
            #pragma unroll
            for (int mi = 0; mi < 2; ++mi)
                acc[g][mi] = __builtin_amdgcn_mfma_f32_16x16x32_f16(ah[mi], b, acc[g][mi], 0, 0, 0);
        }
    }

    // ---- fully in-register epilogue, JIT c/n per 16-row group ----
    const size_t OUTS = (size_t)NROWS * 128;
    const int c = w * 16 + l15;
    const float bic = bi[c], bfc = bfg[c], boc = bo[c], bzc = bz[c];
    const float* cB = cprev + (size_t)row0 * 128 + c;
    const float* nB = nprev + (size_t)row0 * 128 + c;
    float* outB = out + (size_t)row0 * 128 + c;

    #pragma unroll
    for (int mi = 0; mi < 2; ++mi) {
        float cpv[4], npv[4];
        #pragma unroll
        for (int r = 0; r < 4; ++r) {
            int off = (mi * 16 + lg * 4 + r) * 128;
            cpv[r] = cB[off];
            npv[r] = nB[off];
        }
        #pragma unroll
        for (int r = 0; r < 4; ++r) {
            float pit = acc[0][mi][r] + bic;
            float pft = acc[1][mi][r] + bfc;
            float pot = acc[2][mi][r] + boc;
            float pzt = acc[3][mi][r] + bzc;
            float m   = fmaxf(pft, pit);
            float i_t = __expf(pit - m);
            float f_t = __builtin_amdgcn_rcpf(1.0f + __expf(-pft)) + __expf(pft - m);
            float o_t = __builtin_amdgcn_rcpf(1.0f + __expf(-pot));
            float zc  = fminf(fmaxf(pzt, -15.0f), 15.0f);
            float e2  = __expf(2.0f * zc);
            float z_t = (e2 - 1.0f) * __builtin_amdgcn_rcpf(e2 + 1.0f);
            float c_t = f_t * cpv[r] + i_t * z_t;
            float n_t = f_t * npv[r] + i_t;
            float h_t = o_t * c_t * __builtin_amdgcn_rcpf(n_t + 1e-8f);
            int off = (mi * 16 + lg * 4 + r) * 128;
            outB[off]            = h_t;
            outB[OUTS + off]     = c_t;
            outB[2 * OUTS + off] = n_t;
        }
    }
}

extern "C" void kernel_launch(void* const* d_in, const int* in_sizes, int n_in,
                              void* d_out, int out_size, void* d_ws, size_t ws_size,
                              hipStream_t stream) {
    const float* x  = (const float*)d_in[0];
    const float* h  = (const float*)d_in[1];
    const float* cp = (const float*)d_in[2];
    const float* np = (const float*)d_in[3];
    const float* Wi = (const float*)d_in[4];
    const float* Ui = (const float*)d_in[5];
    const float* Wf = (const float*)d_in[6];
    const float* Uf = (const float*)d_in[7];
    const float* Wo = (const float*)d_in[8];
    const float* Uo = (const float*)d_in[9];
    const float* Wz = (const float*)d_in[10];
    const float* Uz = (const float*)d_in[11];
    const float* bi = (const float*)d_in[12];
    const float* bf = (const float*)d_in[13];
    const float* bo = (const float*)d_in[14];
    const float* bz = (const float*)d_in[15];

    ushort* wh = (ushort*)d_ws;                   // 256 KB fp16 fragments

    prep_weights<<<512, 256, 0, stream>>>(Wi, Ui, Wf, Uf, Wo, Uo, Wz, Uz, wh);
    slstm_main<<<NBLKS, 512, 0, stream>>>(x, h, cp, np, bi, bf, bo, bz, wh,
                                          (float*)d_out);
}